// Round 6
// baseline (368.418 us; speedup 1.0000x reference)
//
#include <hip/hip_runtime.h>

#define NNODES 50000
#define NPAD   50048   // 391 * 128; padded row count so 128-tile GEMM staging never faults
#define NEDGES 800000
#define NGRAPH 512
#define DCAP 64   // padded edge slots per node; Poisson(16) max ~37, P(>=64) ~ 1e-23

typedef short bf16x8 __attribute__((ext_vector_type(8)));
typedef unsigned short u16x8 __attribute__((ext_vector_type(8)));
typedef float f32x4 __attribute__((ext_vector_type(4)));
typedef unsigned long long u64;

// async global->LDS, 16B per lane (dest = wave-uniform base + lane*16, linear layout)
#define GLOAD16(g, l)                                                                 \
    __builtin_amdgcn_global_load_lds((const __attribute__((address_space(1))) unsigned*)(g), \
                                     (__attribute__((address_space(3))) unsigned*)(l), 16, 0, 0)

// ---------- bf16 <-> fp32 helpers ----------
static __device__ __forceinline__ float b2f(unsigned short u) {
    return __uint_as_float(((unsigned)u) << 16);
}
static __device__ __forceinline__ unsigned short f2b(float f) {
    unsigned u = __float_as_uint(f);
    unsigned r = (u + 0x7fffu + ((u >> 16) & 1u)) >> 16;  // round-nearest-even
    return (unsigned short)r;
}

// accumulate 8 bf16 (packed in uint4) * c into acc[8]
static __device__ __forceinline__ void accum8(float (&acc)[8], float c, uint4 v) {
    unsigned w[4] = {v.x, v.y, v.z, v.w};
    #pragma unroll
    for (int i = 0; i < 4; ++i) {
        acc[2 * i]     += c * __uint_as_float(w[i] << 16);
        acc[2 * i + 1] += c * __uint_as_float(w[i] & 0xffff0000u);
    }
}

// ---------- init: deg_cnt + gp setup, and all 5 weight transposes via LDS tiles ----------
// W[K][N] fp32 -> WT[N][K] bf16, 64x64 tiles, both global sides coalesced.
// 204 tiles total: W1 4, W2 8, W3 32, Wf1 128, Wf2 32. Blocks >=204 do setup only.
__global__ __launch_bounds__(256) void k_init(const float* __restrict__ W1, const float* __restrict__ W2,
                                              const float* __restrict__ W3, const float* __restrict__ Wf1,
                                              const float* __restrict__ Wf2,
                                              unsigned short* __restrict__ T1, unsigned short* __restrict__ T2,
                                              unsigned short* __restrict__ T3, unsigned short* __restrict__ Tf1,
                                              unsigned short* __restrict__ Tf2,
                                              u64* deg_cnt, int* gp) {
    int i = blockIdx.x * 256 + threadIdx.x;
    if (i < NNODES) deg_cnt[i] = (u64)(1u << 24);   // self-loop w=1 (8.24 fixed)
    if (i < NGRAPH * 512) gp[i] = 0;                // +0.0f bits; relu pool >= 0

    const int b = blockIdx.x;
    if (b >= 204) return;
    const float* W; unsigned short* T; int K, N, t0;
    if (b < 4)        { W = W1;  T = T1;  K = 128;  N = 128;  t0 = 0;   }
    else if (b < 12)  { W = W2;  T = T2;  K = 128;  N = 256;  t0 = 4;   }
    else if (b < 44)  { W = W3;  T = T3;  K = 256;  N = 512;  t0 = 12;  }
    else if (b < 172) { W = Wf1; T = Tf1; K = 512;  N = 1024; t0 = 44;  }
    else              { W = Wf2; T = Tf2; K = 1024; N = 128;  t0 = 172; }
    const int tile = b - t0;
    const int ntn = N >> 6;
    const int k0 = (tile / ntn) * 64, n0 = (tile % ntn) * 64;
    __shared__ float sm[64][65];
    const int t = threadIdx.x;
    const int rr = t >> 6, cc = t & 63;
    #pragma unroll
    for (int r = 0; r < 16; ++r) {
        int kl = r * 4 + rr;
        sm[kl][cc] = W[(size_t)(k0 + kl) * N + n0 + cc];
    }
    __syncthreads();
    #pragma unroll
    for (int r = 0; r < 16; ++r) {
        int nl = r * 4 + rr;
        T[(size_t)(n0 + nl) * K + k0 + cc] = f2b(sm[cc][nl]);
    }
}

// count + DIRECT padded-CSR placement (no scan, no fill pass):
// u64 atomic returns old count = this edge's slot; edges[d*DCAP + slot] = (bf16 ew, src16).
__global__ __launch_bounds__(256) void k_count(const int4* __restrict__ ei_s,
                                               const int4* __restrict__ ei_d,
                                               const float4* __restrict__ ew4,
                                               u64* deg_cnt,
                                               unsigned* __restrict__ edges) {
    int t = blockIdx.x * 256 + threadIdx.x;
    if (t >= NEDGES / 4) return;
    int4 ss = ei_s[t];
    int4 dd = ei_d[t];
    float4 ww = ew4[t];
    int s[4] = {ss.x, ss.y, ss.z, ss.w};
    int d[4] = {dd.x, dd.y, dd.z, dd.w};
    float w[4] = {ww.x, ww.y, ww.z, ww.w};
    int slot[4];
    #pragma unroll
    for (int u = 0; u < 4; ++u) {
        unsigned fixed = __float2uint_rn(w[u] * 16777216.0f);  // 2^24; ew in [0,1)
        u64 old = atomicAdd(&deg_cnt[d[u]], ((u64)1 << 32) | fixed);
        slot[u] = (int)(old >> 32);
        if (slot[u] > DCAP - 1) slot[u] = DCAP - 1;  // never fires (safety)
    }
    #pragma unroll
    for (int u = 0; u < 4; ++u)
        edges[((unsigned)d[u] << 6) | slot[u]] = ((unsigned)f2b(w[u]) << 16) | (unsigned)s[u];
}

// dinv from packed degree
__global__ void k_prep(const u64* __restrict__ deg_cnt, float* __restrict__ dinv) {
    int i = blockIdx.x * 256 + threadIdx.x;
    if (i < NNODES)
        dinv[i] = rsqrtf((float)(unsigned)(deg_cnt[i] & 0xffffffffull) * 5.9604645e-8f);  // *2^-24
}

// fp32 -> bf16 with per-row dinv scale: x'[i,:] = dinv[i]*x[i,:]  (F=128)
__global__ void k_cvt4(const float* __restrict__ X, const float* __restrict__ dinv,
                       unsigned short* __restrict__ Y, int n4) {
    int i = blockIdx.x * 256 + threadIdx.x;
    if (i < n4) {
        float4 v = ((const float4*)X)[i];
        float d = dinv[i >> 5];   // 32 float4 per 128-wide row
        uint2 o;
        o.x = (unsigned)f2b(v.x * d) | ((unsigned)f2b(v.y * d) << 16);
        o.y = (unsigned)f2b(v.z * d) | ((unsigned)f2b(v.w * d) << 16);
        ((uint2*)Y)[i] = o;
    }
}

// ---------- aggregation: Z[d,:] = dinv[d] * (X'[d,:] + sum_e ew_e * X'[src_e,:]) ----------
// wave-per-node (round-2 verified form). Lane-groups of F/8 lanes own one source row ->
// 16B dwordx4 gathers, GRP edges in flight per step, rotating 2-deep pipeline,
// weight-0 masked tail, cross-group shfl reduce, 16B stores by group 0.
template <int F>   // 128 or 256
__global__ __launch_bounds__(256) void k_aggregate(const unsigned short* __restrict__ X,
                                                   const u64* __restrict__ deg_cnt,
                                                   const unsigned* __restrict__ edges,
                                                   const float* __restrict__ dinv,
                                                   unsigned short* __restrict__ Z) {
    constexpr int LPR = F / 8;         // lanes per source row (16 or 32)
    constexpr int GRP = 64 / LPR;      // edges per step (4 or 2)
    constexpr int STEP = GRP * 2;      // edges per pair-iteration (8 or 4)
    const int wave = threadIdx.x >> 6, lane = threadIdx.x & 63;
    const int node = blockIdx.x * 4 + wave;
    if (node >= NNODES) return;
    const int sub = lane & (LPR - 1);
    const int grp = lane / LPR;
    const int fo = sub * 8;
    const unsigned short* Xf = X + fo;
    const float di = dinv[node];
    const int cnt = (int)(deg_cnt[node] >> 32);
    const unsigned* erow = edges + ((unsigned)node << 6);

    // self row: issue early, consumed in epilogue
    const uint4 selfv = *(const uint4*)(Xf + (size_t)node * F);

    float acc[8] = {};

    const int e0 = grp;
    const int nb = (cnt + STEP - 1) / STEP;   // pair-iterations (wave-uniform)

    unsigned pa0 = 0, pb0 = 0, pa1 = 0, pb1 = 0;
    uint4 va0 = {}, vb0 = {};
    if (nb > 0) {
        int ea = e0, eb = e0 + GRP;
        pa0 = (ea < cnt) ? erow[ea] : 0u;
        pb0 = (eb < cnt) ? erow[eb] : 0u;
        va0 = *(const uint4*)(Xf + (size_t)(pa0 & 0xffffu) * F);
        vb0 = *(const uint4*)(Xf + (size_t)(pb0 & 0xffffu) * F);
        if (nb > 1) {
            int ea1 = e0 + STEP, eb1 = ea1 + GRP;
            pa1 = (ea1 < cnt) ? erow[ea1] : 0u;
            pb1 = (eb1 < cnt) ? erow[eb1] : 0u;
        }
    }
    for (int p = 0; p < nb; ++p) {
        uint4 va1 = {}, vb1 = {};
        unsigned pa2 = 0, pb2 = 0;
        if (p + 1 < nb) {
            va1 = *(const uint4*)(Xf + (size_t)(pa1 & 0xffffu) * F);
            vb1 = *(const uint4*)(Xf + (size_t)(pb1 & 0xffffu) * F);
            if (p + 2 < nb) {
                int ea = e0 + (p + 2) * STEP, eb = ea + GRP;
                pa2 = (ea < cnt) ? erow[ea] : 0u;
                pb2 = (eb < cnt) ? erow[eb] : 0u;
            }
        }
        accum8(acc, b2f((unsigned short)(pa0 >> 16)), va0);
        accum8(acc, b2f((unsigned short)(pb0 >> 16)), vb0);
        pa0 = pa1; pb0 = pb1; va0 = va1; vb0 = vb1;
        pa1 = pa2; pb1 = pb2;
    }

    // cross-group reduce
    #pragma unroll
    for (int j = 0; j < 8; ++j) {
        if constexpr (GRP == 4) acc[j] += __shfl_xor(acc[j], 16, 64);
        acc[j] += __shfl_xor(acc[j], 32, 64);
    }

    if (grp == 0) {
        unsigned w[4] = {selfv.x, selfv.y, selfv.z, selfv.w};
        unsigned o[4];
        #pragma unroll
        for (int i = 0; i < 4; ++i) {
            float s0 = __uint_as_float(w[i] << 16);
            float s1 = __uint_as_float(w[i] & 0xffff0000u);
            unsigned short c0 = f2b(di * (acc[2 * i] + s0));
            unsigned short c1 = f2b(di * (acc[2 * i + 1] + s1));
            o[i] = (unsigned)c0 | ((unsigned)c1 << 16);
        }
        uint4 ov; ov.x = o[0]; ov.y = o[1]; ov.z = o[2]; ov.w = o[3];
        *(uint4*)(Z + (size_t)node * F + fo) = ov;
    }
}

// ---------- m97-structure GEMM: 128x128 tile, global_load_lds staging ----------
// 4 waves (2x2), each 64x64 = 4x4 16x16x32 fragments. BK=32, linear LDS [128][32].
// A rows must be readable up to next multiple of 128 (NPAD padding); OOB-row garbage
// only pollutes accumulators that are discarded by row<M guards.
// Bijective XCD chunking (m204): each XCD owns a contiguous m-range for all n-blocks ->
// A panel fetched ~once per XCD; B stays L2-hot per XCD.
// CMODE 0: bf16 store + relu + optional rscale. 2: fused per-graph relu+max-pool.
template <int CMODE>
__global__ __launch_bounds__(256) void k_gemm128(const unsigned short* __restrict__ A,
                                                 const unsigned short* __restrict__ WT,
                                                 const float* __restrict__ bias,
                                                 unsigned short* __restrict__ C,
                                                 const int* __restrict__ batch,
                                                 int* __restrict__ gp,
                                                 const float* __restrict__ rscale,
                                                 int M, int N, int K) {
    __shared__ unsigned short As[128 * 32];
    __shared__ unsigned short Bs[128 * 32];
    const int tid = threadIdx.x;

    // bijective XCD remap of flat block id (xcd = f % 8 under round-robin dispatch)
    const int nwg = gridDim.x * gridDim.y;
    const int f = blockIdx.y * gridDim.x + blockIdx.x;
    const int q = nwg >> 3, r = nwg & 7;
    const int xcd = f & 7, idx = f >> 3;
    const int w = (xcd < r) ? xcd * (q + 1) + idx : r * (q + 1) + (xcd - r) * q + idx;
    const int m0 = (w / gridDim.x) * 128;
    const int n0 = (w % gridDim.x) * 128;

    const int wave = tid >> 6, lane = tid & 63;
    const int wm = (wave >> 1) * 64, wn = (wave & 1) * 64;
    const int quad = lane >> 4, mrow = lane & 15;

    const int sr = tid >> 2;              // staging row 0..63
    const int sc = (tid & 3) * 8;         // staging col (shorts)
    const unsigned short* Ag0 = A + (size_t)(m0 + sr) * K + sc;
    const unsigned short* Ag1 = A + (size_t)(m0 + 64 + sr) * K + sc;
    const unsigned short* Bg0 = WT + (size_t)(n0 + sr) * K + sc;
    const unsigned short* Bg1 = WT + (size_t)(n0 + 64 + sr) * K + sc;
    unsigned short* Ad0 = &As[sr * 32 + sc];
    unsigned short* Ad1 = &As[(64 + sr) * 32 + sc];
    unsigned short* Bd0 = &Bs[sr * 32 + sc];
    unsigned short* Bd1 = &Bs[(64 + sr) * 32 + sc];

    f32x4 acc[4][4] = {};

    for (int k0 = 0; k0 < K; k0 += 32) {
        GLOAD16(Ag0 + k0, Ad0);
        GLOAD16(Ag1 + k0, Ad1);
        GLOAD16(Bg0 + k0, Bd0);
        GLOAD16(Bg1 + k0, Bd1);
        __syncthreads();   // drains vmcnt before barrier
        bf16x8 af[4], bf[4];
        #pragma unroll
        for (int mt = 0; mt < 4; ++mt)
            af[mt] = *(const bf16x8*)&As[(wm + mt * 16 + mrow) * 32 + quad * 8];
        #pragma unroll
        for (int nt = 0; nt < 4; ++nt)
            bf[nt] = *(const bf16x8*)&Bs[(wn + nt * 16 + mrow) * 32 + quad * 8];
        #pragma unroll
        for (int mt = 0; mt < 4; ++mt)
            #pragma unroll
            for (int nt = 0; nt < 4; ++nt)
                acc[mt][nt] = __builtin_amdgcn_mfma_f32_16x16x32_bf16(af[mt], bf[nt], acc[mt][nt], 0, 0, 0);
        __syncthreads();
    }

    float bn[4];
    #pragma unroll
    for (int nt = 0; nt < 4; ++nt) bn[nt] = bias[n0 + wn + nt * 16 + mrow];

    if constexpr (CMODE == 0) {
        #pragma unroll
        for (int mt = 0; mt < 4; ++mt) {
            #pragma unroll
            for (int r4 = 0; r4 < 4; ++r4) {
                int row = m0 + wm + mt * 16 + quad * 4 + r4;
                if (row < M) {
                    float rs = rscale ? rscale[row] : 1.0f;
                    #pragma unroll
                    for (int nt = 0; nt < 4; ++nt) {
                        float v = fmaxf(acc[mt][nt][r4] + bn[nt], 0.f) * rs;
                        C[(size_t)row * N + n0 + wn + nt * 16 + mrow] = f2b(v);
                    }
                }
            }
        }
    } else {
        // per-wave pool: wave covers 64 rows -> spans <=2 graphs (min graph size 97)
        const int wr0 = m0 + wm;
        int g0i = wr0 < M ? wr0 : M - 1;
        const int g0 = batch[g0i];
        int lastr = wr0 + 63; if (lastr >= M) lastr = M - 1;
        const int gl = batch[lastr];
        bool rok[16]; int gid[16];
        #pragma unroll
        for (int mt = 0; mt < 4; ++mt)
            #pragma unroll
            for (int r4 = 0; r4 < 4; ++r4) {
                int row = wr0 + mt * 16 + quad * 4 + r4;
                rok[mt * 4 + r4] = row < M;
                gid[mt * 4 + r4] = (row < M) ? batch[row] : -1;
            }
        #pragma unroll
        for (int nt = 0; nt < 4; ++nt) {
            float v0 = 0.f, v1 = 0.f;
            #pragma unroll
            for (int mt = 0; mt < 4; ++mt)
                #pragma unroll
                for (int r4 = 0; r4 < 4; ++r4)
                    if (rok[mt * 4 + r4]) {
                        float v = fmaxf(acc[mt][nt][r4] + bn[nt], 0.f);
                        if (gid[mt * 4 + r4] == g0) v0 = fmaxf(v0, v);
                        else v1 = fmaxf(v1, v);
                    }
            v0 = fmaxf(v0, __shfl_xor(v0, 16, 64));
            v0 = fmaxf(v0, __shfl_xor(v0, 32, 64));
            v1 = fmaxf(v1, __shfl_xor(v1, 16, 64));
            v1 = fmaxf(v1, __shfl_xor(v1, 32, 64));
            if (quad == 0) {
                int c = n0 + wn + nt * 16 + mrow;
                atomicMax(&gp[(size_t)g0 * N + c], __float_as_int(v0));
                if (gl != g0) atomicMax(&gp[(size_t)gl * N + c], __float_as_int(v1));
            }
        }
    }
}

// ---------- legacy GEMM for the small MLP head (M=512) ----------
// block 64(M) x 128(N), 4 waves (2x2 of 32x64), BK=32, 16x16x32 MFMA.
// CMODE 0: bf16 store + relu. 1: fp32 store, no relu. AFP: A is fp32.
template <int CMODE, int AFP>
__global__ __launch_bounds__(256) void k_gemm_mfma(const void* __restrict__ Av,
                                                   const unsigned short* __restrict__ WT,
                                                   const float* __restrict__ bias,
                                                   void* __restrict__ Cv,
                                                   int M, int N, int K) {
    constexpr int LDK = 40;
    __shared__ unsigned short As[64 * LDK];
    __shared__ unsigned short Bs[128 * LDK];
    const int tid = threadIdx.x;
    const int m0 = blockIdx.y * 64, n0 = blockIdx.x * 128;
    const int wave = tid >> 6, lane = tid & 63;
    const int wm = (wave >> 1) * 32;
    const int wn = (wave & 1) * 64;
    const int quad = lane >> 4, mrow = lane & 15;

    const int ar = tid >> 2;
    const int ak = (tid & 3) * 8;
    const bool arow_ok = (m0 + ar) < M;
    const size_t aoff = (size_t)(m0 + ar) * K + ak;
    const unsigned short* Bg0 = WT + (size_t)(n0 + ar) * K + ak;
    const unsigned short* Bg1 = WT + (size_t)(n0 + ar + 64) * K + ak;

    f32x4 acc[2][4] = {};

    for (int k0 = 0; k0 < K; k0 += 32) {
        u16x8 av = {};
        if (arow_ok) {
            if constexpr (AFP) {
                const float* Af = (const float*)Av + aoff + k0;
                float4 f0 = *(const float4*)Af;
                float4 f1 = *(const float4*)(Af + 4);
                av[0] = (short)f2b(f0.x); av[1] = (short)f2b(f0.y);
                av[2] = (short)f2b(f0.z); av[3] = (short)f2b(f0.w);
                av[4] = (short)f2b(f1.x); av[5] = (short)f2b(f1.y);
                av[6] = (short)f2b(f1.z); av[7] = (short)f2b(f1.w);
            } else {
                av = *(const u16x8*)((const unsigned short*)Av + aoff + k0);
            }
        }
        u16x8 bv0 = *(const u16x8*)(Bg0 + k0);
        u16x8 bv1 = *(const u16x8*)(Bg1 + k0);
        *(u16x8*)&As[ar * LDK + ak] = av;
        *(u16x8*)&Bs[ar * LDK + ak] = bv0;
        *(u16x8*)&Bs[(ar + 64) * LDK + ak] = bv1;
        __syncthreads();
        bf16x8 af[2], bf[4];
        #pragma unroll
        for (int mt = 0; mt < 2; ++mt)
            af[mt] = *(const bf16x8*)&As[(wm + mt * 16 + mrow) * LDK + quad * 8];
        #pragma unroll
        for (int nt = 0; nt < 4; ++nt)
            bf[nt] = *(const bf16x8*)&Bs[(wn + nt * 16 + mrow) * LDK + quad * 8];
        #pragma unroll
        for (int mt = 0; mt < 2; ++mt)
            #pragma unroll
            for (int nt = 0; nt < 4; ++nt)
                acc[mt][nt] = __builtin_amdgcn_mfma_f32_16x16x32_bf16(af[mt], bf[nt], acc[mt][nt], 0, 0, 0);
        __syncthreads();
    }

    float bn[4];
    #pragma unroll
    for (int nt = 0; nt < 4; ++nt) bn[nt] = bias[n0 + wn + nt * 16 + mrow];

    if constexpr (CMODE == 0) {
        unsigned short* C = (unsigned short*)Cv;
        #pragma unroll
        for (int mt = 0; mt < 2; ++mt) {
            #pragma unroll
            for (int r = 0; r < 4; ++r) {
                int row = m0 + wm + mt * 16 + quad * 4 + r;
                if (row < M) {
                    #pragma unroll
                    for (int nt = 0; nt < 4; ++nt) {
                        float v = fmaxf(acc[mt][nt][r] + bn[nt], 0.f);
                        C[(size_t)row * N + n0 + wn + nt * 16 + mrow] = f2b(v);
                    }
                }
            }
        }
    } else {
        float* C = (float*)Cv;
        #pragma unroll
        for (int mt = 0; mt < 2; ++mt) {
            #pragma unroll
            for (int r = 0; r < 4; ++r) {
                int row = m0 + wm + mt * 16 + quad * 4 + r;
                if (row < M) {
                    #pragma unroll
                    for (int nt = 0; nt < 4; ++nt)
                        C[(size_t)row * N + n0 + wn + nt * 16 + mrow] = acc[mt][nt][r] + bn[nt];
                }
            }
        }
    }
}

extern "C" void kernel_launch(void* const* d_in, const int* in_sizes, int n_in,
                              void* d_out, int out_size, void* d_ws, size_t ws_size,
                              hipStream_t stream) {
    const float* x   = (const float*)d_in[0];
    const float* ew  = (const float*)d_in[1];
    const float* W1  = (const float*)d_in[2];
    const float* b1  = (const float*)d_in[3];
    const float* W2  = (const float*)d_in[4];
    const float* b2  = (const float*)d_in[5];
    const float* W3  = (const float*)d_in[6];
    const float* b3  = (const float*)d_in[7];
    const float* Wf1 = (const float*)d_in[8];
    const float* bf1 = (const float*)d_in[9];
    const float* Wf2 = (const float*)d_in[10];
    const float* bf2 = (const float*)d_in[11];
    const int* ei    = (const int*)d_in[12];
    const int* batch = (const int*)d_in[13];
    float* out = (float*)d_out;
    (void)in_sizes; (void)n_in; (void)out_size; (void)ws_size;

    char* p = (char*)d_ws;
    auto alloc = [&](size_t bytes) -> char* {
        char* r = p;
        p += (bytes + 255) & ~(size_t)255;
        return r;
    };
    const int nbN = (NNODES + 255) / 256;   // 196
    u64*   deg_cnt = (u64*)alloc((size_t)NNODES * 8);
    float* dinv   = (float*)alloc((size_t)NNODES * 4);
    unsigned* edges = (unsigned*)alloc((size_t)NNODES * DCAP * 4);  // padded CSR, 12.8 MB
    int*   gp     = (int*)  alloc((size_t)NGRAPH * 512 * 4);
    unsigned short* f1   = (unsigned short*)alloc((size_t)NGRAPH * 1024 * 2);
    unsigned short* wt1  = (unsigned short*)alloc((size_t)128 * 128 * 2);
    unsigned short* wt2  = (unsigned short*)alloc((size_t)256 * 128 * 2);
    unsigned short* wt3  = (unsigned short*)alloc((size_t)512 * 256 * 2);
    unsigned short* wtf1 = (unsigned short*)alloc((size_t)1024 * 512 * 2);
    unsigned short* wtf2 = (unsigned short*)alloc((size_t)128 * 1024 * 2);
    unsigned short* bufA = (unsigned short*)alloc((size_t)NPAD * 256 * 2);
    unsigned short* bufB = (unsigned short*)alloc((size_t)NPAD * 256 * 2);
    unsigned short* x16  = bufB;   // consumed by agg-1 before gemm-1 overwrites bufB
    // total ~68 MB

    const int MB128 = (NNODES + 127) / 128; // 391
    const int AGG = (NNODES + 3) / 4;       // 12500

    // graph preprocessing: 4 kernels
    k_init<<<1024, 256, 0, stream>>>(W1, W2, W3, Wf1, Wf2,
                                     wt1, wt2, wt3, wtf1, wtf2, deg_cnt, gp);
    k_count<<<(NEDGES / 4 + 255) / 256, 256, 0, stream>>>(
        (const int4*)ei, (const int4*)(ei + NEDGES), (const float4*)ew, deg_cnt, edges);
    k_prep<<<nbN, 256, 0, stream>>>(deg_cnt, dinv);
    k_cvt4<<<(NNODES * 32 + 255) / 256, 256, 0, stream>>>(x, dinv, x16, NNODES * 32);

    // layer 1: Z1 = dinv*(x' + A@x'); h1' = dinv*relu(Z1@W1+b1)
    k_aggregate<128><<<AGG, 256, 0, stream>>>(x16, deg_cnt, edges, dinv, bufA);
    k_gemm128<0><<<dim3(1, MB128), 256, 0, stream>>>(bufA, wt1, b1, bufB, nullptr, nullptr, dinv, NNODES, 128, 128);
    // layer 2
    k_aggregate<128><<<AGG, 256, 0, stream>>>(bufB, deg_cnt, edges, dinv, bufA);
    k_gemm128<0><<<dim3(2, MB128), 256, 0, stream>>>(bufA, wt2, b2, bufB, nullptr, nullptr, dinv, NNODES, 256, 128);
    // layer 3 + fused pool (unscaled relu feeds the pool)
    k_aggregate<256><<<AGG, 256, 0, stream>>>(bufB, deg_cnt, edges, dinv, bufA);
    k_gemm128<2><<<dim3(4, MB128), 256, 0, stream>>>(bufA, wt3, b3, nullptr, batch, gp, nullptr, NNODES, 512, 256);

    // MLP head (legacy kernel, M=512)
    k_gemm_mfma<0, 1><<<dim3(8, NGRAPH / 64), 256, 0, stream>>>(gp, wtf1, bf1, f1, NGRAPH, 1024, 512);
    k_gemm_mfma<1, 0><<<dim3(1, NGRAPH / 64), 256, 0, stream>>>(f1, wtf2, bf2, out, NGRAPH, 128, 1024);
}

// Round 7
// 365.416 us; speedup vs baseline: 1.0082x; 1.0082x over previous
//
#include <hip/hip_runtime.h>

#define NNODES 50000
#define NPAD   50048   // 391 * 128; padded row count so 128-tile GEMM staging never faults
#define NEDGES 800000
#define NGRAPH 512
#define DCAP 64   // padded edge slots per node; Poisson(16) max ~37, P(>=64) ~ 1e-23

typedef short bf16x8 __attribute__((ext_vector_type(8)));
typedef unsigned short u16x8 __attribute__((ext_vector_type(8)));
typedef float f32x4 __attribute__((ext_vector_type(4)));
typedef unsigned long long u64;

// async global->LDS, 16B per lane (dest = wave-uniform base + lane*16, linear layout)
#define GLOAD16(g, l)                                                                 \
    __builtin_amdgcn_global_load_lds((const __attribute__((address_space(1))) unsigned*)(g), \
                                     (__attribute__((address_space(3))) unsigned*)(l), 16, 0, 0)

// ---------- bf16 <-> fp32 helpers ----------
static __device__ __forceinline__ float b2f(unsigned short u) {
    return __uint_as_float(((unsigned)u) << 16);
}
static __device__ __forceinline__ unsigned short f2b(float f) {
    unsigned u = __float_as_uint(f);
    unsigned r = (u + 0x7fffu + ((u >> 16) & 1u)) >> 16;  // round-nearest-even
    return (unsigned short)r;
}

// accumulate 8 bf16 (packed in uint4) * c into acc[8]
static __device__ __forceinline__ void accum8(float (&acc)[8], float c, uint4 v) {
    unsigned w[4] = {v.x, v.y, v.z, v.w};
    #pragma unroll
    for (int i = 0; i < 4; ++i) {
        acc[2 * i]     += c * __uint_as_float(w[i] << 16);
        acc[2 * i + 1] += c * __uint_as_float(w[i] & 0xffff0000u);
    }
}

// ---------- init: deg_cnt + gp setup, and all 5 weight transposes via LDS tiles ----------
// W[K][N] fp32 -> WT[N][K] bf16, 64x64 tiles, both global sides coalesced.
// 204 tiles total: W1 4, W2 8, W3 32, Wf1 128, Wf2 32. Blocks >=204 do setup only.
__global__ __launch_bounds__(256) void k_init(const float* __restrict__ W1, const float* __restrict__ W2,
                                              const float* __restrict__ W3, const float* __restrict__ Wf1,
                                              const float* __restrict__ Wf2,
                                              unsigned short* __restrict__ T1, unsigned short* __restrict__ T2,
                                              unsigned short* __restrict__ T3, unsigned short* __restrict__ Tf1,
                                              unsigned short* __restrict__ Tf2,
                                              u64* deg_cnt, int* gp) {
    int i = blockIdx.x * 256 + threadIdx.x;
    if (i < NNODES) deg_cnt[i] = (u64)(1u << 24);   // self-loop w=1 (8.24 fixed)
    if (i < NGRAPH * 512) gp[i] = 0;                // +0.0f bits; relu pool >= 0

    const int b = blockIdx.x;
    if (b >= 204) return;
    const float* W; unsigned short* T; int K, N, t0;
    if (b < 4)        { W = W1;  T = T1;  K = 128;  N = 128;  t0 = 0;   }
    else if (b < 12)  { W = W2;  T = T2;  K = 128;  N = 256;  t0 = 4;   }
    else if (b < 44)  { W = W3;  T = T3;  K = 256;  N = 512;  t0 = 12;  }
    else if (b < 172) { W = Wf1; T = Tf1; K = 512;  N = 1024; t0 = 44;  }
    else              { W = Wf2; T = Tf2; K = 1024; N = 128;  t0 = 172; }
    const int tile = b - t0;
    const int ntn = N >> 6;
    const int k0 = (tile / ntn) * 64, n0 = (tile % ntn) * 64;
    __shared__ float sm[64][65];
    const int t = threadIdx.x;
    const int rr = t >> 6, cc = t & 63;
    #pragma unroll
    for (int r = 0; r < 16; ++r) {
        int kl = r * 4 + rr;
        sm[kl][cc] = W[(size_t)(k0 + kl) * N + n0 + cc];
    }
    __syncthreads();
    #pragma unroll
    for (int r = 0; r < 16; ++r) {
        int nl = r * 4 + rr;
        T[(size_t)(n0 + nl) * K + k0 + cc] = f2b(sm[cc][nl]);
    }
}

// count + DIRECT padded-CSR placement (no scan, no fill pass):
// u64 atomic returns old count = this edge's slot; edges[d*DCAP + slot] = (bf16 ew, src16).
__global__ __launch_bounds__(256) void k_count(const int4* __restrict__ ei_s,
                                               const int4* __restrict__ ei_d,
                                               const float4* __restrict__ ew4,
                                               u64* deg_cnt,
                                               unsigned* __restrict__ edges) {
    int t = blockIdx.x * 256 + threadIdx.x;
    if (t >= NEDGES / 4) return;
    int4 ss = ei_s[t];
    int4 dd = ei_d[t];
    float4 ww = ew4[t];
    int s[4] = {ss.x, ss.y, ss.z, ss.w};
    int d[4] = {dd.x, dd.y, dd.z, dd.w};
    float w[4] = {ww.x, ww.y, ww.z, ww.w};
    int slot[4];
    #pragma unroll
    for (int u = 0; u < 4; ++u) {
        unsigned fixed = __float2uint_rn(w[u] * 16777216.0f);  // 2^24; ew in [0,1)
        u64 old = atomicAdd(&deg_cnt[d[u]], ((u64)1 << 32) | fixed);
        slot[u] = (int)(old >> 32);
        if (slot[u] > DCAP - 1) slot[u] = DCAP - 1;  // never fires (safety)
    }
    #pragma unroll
    for (int u = 0; u < 4; ++u)
        edges[((unsigned)d[u] << 6) | slot[u]] = ((unsigned)f2b(w[u]) << 16) | (unsigned)s[u];
}

// fp32 -> bf16 with per-row dinv scale (computed inline from deg_cnt; also writes dinv[])
__global__ void k_cvt_prep(const float* __restrict__ X, const u64* __restrict__ deg_cnt,
                           float* __restrict__ dinv, unsigned short* __restrict__ Y, int n4) {
    int i = blockIdx.x * 256 + threadIdx.x;
    if (i < n4) {
        int row = i >> 5;   // 32 float4 per 128-wide row
        float d = rsqrtf((float)(unsigned)(deg_cnt[row] & 0xffffffffull) * 5.9604645e-8f);
        if ((i & 31) == 0) dinv[row] = d;
        float4 v = ((const float4*)X)[i];
        uint2 o;
        o.x = (unsigned)f2b(v.x * d) | ((unsigned)f2b(v.y * d) << 16);
        o.y = (unsigned)f2b(v.z * d) | ((unsigned)f2b(v.w * d) << 16);
        ((uint2*)Y)[i] = o;
    }
}

// ---------- aggregation: Z[d,:] = dinv[d] * (X'[d,:] + sum_e ew_e * X'[src_e,:]) ----------
// wave-per-node (round-2 verified form). Lane-groups of F/8 lanes own one source row ->
// 16B dwordx4 gathers, GRP edges in flight per step, rotating 2-deep pipeline,
// weight-0 masked tail, cross-group shfl reduce, 16B stores by group 0.
template <int F>   // 128 or 256
__global__ __launch_bounds__(256) void k_aggregate(const unsigned short* __restrict__ X,
                                                   const u64* __restrict__ deg_cnt,
                                                   const unsigned* __restrict__ edges,
                                                   const float* __restrict__ dinv,
                                                   unsigned short* __restrict__ Z) {
    constexpr int LPR = F / 8;         // lanes per source row (16 or 32)
    constexpr int GRP = 64 / LPR;      // edges per step (4 or 2)
    constexpr int STEP = GRP * 2;      // edges per pair-iteration (8 or 4)
    const int wave = threadIdx.x >> 6, lane = threadIdx.x & 63;
    const int node = blockIdx.x * 4 + wave;
    if (node >= NNODES) return;
    const int sub = lane & (LPR - 1);
    const int grp = lane / LPR;
    const int fo = sub * 8;
    const unsigned short* Xf = X + fo;
    const float di = dinv[node];
    const int cnt = (int)(deg_cnt[node] >> 32);
    const unsigned* erow = edges + ((unsigned)node << 6);

    // self row: issue early, consumed in epilogue
    const uint4 selfv = *(const uint4*)(Xf + (size_t)node * F);

    float acc[8] = {};

    const int e0 = grp;
    const int nb = (cnt + STEP - 1) / STEP;   // pair-iterations (wave-uniform)

    unsigned pa0 = 0, pb0 = 0, pa1 = 0, pb1 = 0;
    uint4 va0 = {}, vb0 = {};
    if (nb > 0) {
        int ea = e0, eb = e0 + GRP;
        pa0 = (ea < cnt) ? erow[ea] : 0u;
        pb0 = (eb < cnt) ? erow[eb] : 0u;
        va0 = *(const uint4*)(Xf + (size_t)(pa0 & 0xffffu) * F);
        vb0 = *(const uint4*)(Xf + (size_t)(pb0 & 0xffffu) * F);
        if (nb > 1) {
            int ea1 = e0 + STEP, eb1 = ea1 + GRP;
            pa1 = (ea1 < cnt) ? erow[ea1] : 0u;
            pb1 = (eb1 < cnt) ? erow[eb1] : 0u;
        }
    }
    for (int p = 0; p < nb; ++p) {
        uint4 va1 = {}, vb1 = {};
        unsigned pa2 = 0, pb2 = 0;
        if (p + 1 < nb) {
            va1 = *(const uint4*)(Xf + (size_t)(pa1 & 0xffffu) * F);
            vb1 = *(const uint4*)(Xf + (size_t)(pb1 & 0xffffu) * F);
            if (p + 2 < nb) {
                int ea = e0 + (p + 2) * STEP, eb = ea + GRP;
                pa2 = (ea < cnt) ? erow[ea] : 0u;
                pb2 = (eb < cnt) ? erow[eb] : 0u;
            }
        }
        accum8(acc, b2f((unsigned short)(pa0 >> 16)), va0);
        accum8(acc, b2f((unsigned short)(pb0 >> 16)), vb0);
        pa0 = pa1; pb0 = pb1; va0 = va1; vb0 = vb1;
        pa1 = pa2; pb1 = pb2;
    }

    // cross-group reduce
    #pragma unroll
    for (int j = 0; j < 8; ++j) {
        if constexpr (GRP == 4) acc[j] += __shfl_xor(acc[j], 16, 64);
        acc[j] += __shfl_xor(acc[j], 32, 64);
    }

    if (grp == 0) {
        unsigned w[4] = {selfv.x, selfv.y, selfv.z, selfv.w};
        unsigned o[4];
        #pragma unroll
        for (int i = 0; i < 4; ++i) {
            float s0 = __uint_as_float(w[i] << 16);
            float s1 = __uint_as_float(w[i] & 0xffff0000u);
            unsigned short c0 = f2b(di * (acc[2 * i] + s0));
            unsigned short c1 = f2b(di * (acc[2 * i + 1] + s1));
            o[i] = (unsigned)c0 | ((unsigned)c1 << 16);
        }
        uint4 ov; ov.x = o[0]; ov.y = o[1]; ov.z = o[2]; ov.w = o[3];
        *(uint4*)(Z + (size_t)node * F + fo) = ov;
    }
}

// ---------- m97-structure GEMM, 2-phase double-buffered (T3-minimum) ----------
// 128x128 tile, 4 waves (2x2), each 64x64 = 4x4 16x16x32 fragments. BK=32.
// Double-buffered linear LDS [2][128][32]; next tile's global_load_lds issued BEFORE
// current tile's ds_read+MFMA -> loads fly under compute; one vmcnt-drain barrier/tile.
// A rows readable up to next multiple of 128 (NPAD); OOB-row garbage only pollutes
// accumulators discarded by row<M guards.
// Bijective XCD chunking (m204): each XCD owns a contiguous m-range for all n-blocks.
// CMODE 0: bf16 store + relu + optional rscale. 2: fused per-graph relu+max-pool.
template <int CMODE>
__global__ __launch_bounds__(256) void k_gemm128(const unsigned short* __restrict__ A,
                                                 const unsigned short* __restrict__ WT,
                                                 const float* __restrict__ bias,
                                                 unsigned short* __restrict__ C,
                                                 const int* __restrict__ batch,
                                                 int* __restrict__ gp,
                                                 const float* __restrict__ rscale,
                                                 int M, int N, int K) {
    __shared__ unsigned short As[2][128 * 32];
    __shared__ unsigned short Bs[2][128 * 32];
    const int tid = threadIdx.x;

    // bijective XCD remap of flat block id (xcd = f % 8 under round-robin dispatch)
    const int nwg = gridDim.x * gridDim.y;
    const int f = blockIdx.y * gridDim.x + blockIdx.x;
    const int q = nwg >> 3, r = nwg & 7;
    const int xcd = f & 7, idx = f >> 3;
    const int w = (xcd < r) ? xcd * (q + 1) + idx : r * (q + 1) + (xcd - r) * q + idx;
    const int m0 = (w / gridDim.x) * 128;
    const int n0 = (w % gridDim.x) * 128;

    const int wave = tid >> 6, lane = tid & 63;
    const int wm = (wave >> 1) * 64, wn = (wave & 1) * 64;
    const int quad = lane >> 4, mrow = lane & 15;

    const int sr = tid >> 2;              // staging row 0..63
    const int sc = (tid & 3) * 8;         // staging col (shorts)
    const unsigned short* Ag0 = A + (size_t)(m0 + sr) * K + sc;
    const unsigned short* Ag1 = A + (size_t)(m0 + 64 + sr) * K + sc;
    const unsigned short* Bg0 = WT + (size_t)(n0 + sr) * K + sc;
    const unsigned short* Bg1 = WT + (size_t)(n0 + 64 + sr) * K + sc;
    const int so0 = sr * 32 + sc, so1 = (64 + sr) * 32 + sc;

    f32x4 acc[4][4] = {};
    const int nsteps = K >> 5;

    // prologue: stage tile 0 into buffer 0
    GLOAD16(Ag0, &As[0][so0]);
    GLOAD16(Ag1, &As[0][so1]);
    GLOAD16(Bg0, &Bs[0][so0]);
    GLOAD16(Bg1, &Bs[0][so1]);
    __syncthreads();   // vmcnt(0) drain + barrier

    for (int step = 0; step < nsteps; ++step) {
        const int cur = step & 1;
        if (step + 1 < nsteps) {           // issue next tile while computing current
            const int k1 = (step + 1) << 5;
            GLOAD16(Ag0 + k1, &As[cur ^ 1][so0]);
            GLOAD16(Ag1 + k1, &As[cur ^ 1][so1]);
            GLOAD16(Bg0 + k1, &Bs[cur ^ 1][so0]);
            GLOAD16(Bg1 + k1, &Bs[cur ^ 1][so1]);
        }
        bf16x8 af[4], bf[4];
        #pragma unroll
        for (int mt = 0; mt < 4; ++mt)
            af[mt] = *(const bf16x8*)&As[cur][(wm + mt * 16 + mrow) * 32 + quad * 8];
        #pragma unroll
        for (int nt = 0; nt < 4; ++nt)
            bf[nt] = *(const bf16x8*)&Bs[cur][(wn + nt * 16 + mrow) * 32 + quad * 8];
        #pragma unroll
        for (int mt = 0; mt < 4; ++mt)
            #pragma unroll
            for (int nt = 0; nt < 4; ++nt)
                acc[mt][nt] = __builtin_amdgcn_mfma_f32_16x16x32_bf16(af[mt], bf[nt], acc[mt][nt], 0, 0, 0);
        __syncthreads();   // drains prefetch vmcnt + this tile's lgkm; gates buffer reuse
    }

    float bn[4];
    #pragma unroll
    for (int nt = 0; nt < 4; ++nt) bn[nt] = bias[n0 + wn + nt * 16 + mrow];

    if constexpr (CMODE == 0) {
        #pragma unroll
        for (int mt = 0; mt < 4; ++mt) {
            #pragma unroll
            for (int r4 = 0; r4 < 4; ++r4) {
                int row = m0 + wm + mt * 16 + quad * 4 + r4;
                if (row < M) {
                    float rs = rscale ? rscale[row] : 1.0f;
                    #pragma unroll
                    for (int nt = 0; nt < 4; ++nt) {
                        float v = fmaxf(acc[mt][nt][r4] + bn[nt], 0.f) * rs;
                        C[(size_t)row * N + n0 + wn + nt * 16 + mrow] = f2b(v);
                    }
                }
            }
        }
    } else {
        // per-wave pool: wave covers 64 rows -> spans <=2 graphs (min graph size 97)
        const int wr0 = m0 + wm;
        int g0i = wr0 < M ? wr0 : M - 1;
        const int g0 = batch[g0i];
        int lastr = wr0 + 63; if (lastr >= M) lastr = M - 1;
        const int gl = batch[lastr];
        bool rok[16]; int gid[16];
        #pragma unroll
        for (int mt = 0; mt < 4; ++mt)
            #pragma unroll
            for (int r4 = 0; r4 < 4; ++r4) {
                int row = wr0 + mt * 16 + quad * 4 + r4;
                rok[mt * 4 + r4] = row < M;
                gid[mt * 4 + r4] = (row < M) ? batch[row] : -1;
            }
        #pragma unroll
        for (int nt = 0; nt < 4; ++nt) {
            float v0 = 0.f, v1 = 0.f;
            #pragma unroll
            for (int mt = 0; mt < 4; ++mt)
                #pragma unroll
                for (int r4 = 0; r4 < 4; ++r4)
                    if (rok[mt * 4 + r4]) {
                        float v = fmaxf(acc[mt][nt][r4] + bn[nt], 0.f);
                        if (gid[mt * 4 + r4] == g0) v0 = fmaxf(v0, v);
                        else v1 = fmaxf(v1, v);
                    }
            v0 = fmaxf(v0, __shfl_xor(v0, 16, 64));
            v0 = fmaxf(v0, __shfl_xor(v0, 32, 64));
            v1 = fmaxf(v1, __shfl_xor(v1, 16, 64));
            v1 = fmaxf(v1, __shfl_xor(v1, 32, 64));
            if (quad == 0) {
                int c = n0 + wn + nt * 16 + mrow;
                atomicMax(&gp[(size_t)g0 * N + c], __float_as_int(v0));
                if (gl != g0) atomicMax(&gp[(size_t)gl * N + c], __float_as_int(v1));
            }
        }
    }
}

// ---------- legacy GEMM for the small MLP head (M=512) ----------
// block 64(M) x 128(N), 4 waves (2x2 of 32x64), BK=32, 16x16x32 MFMA.
// CMODE 0: bf16 store + relu. 1: fp32 store, no relu. AFP: A is fp32.
template <int CMODE, int AFP>
__global__ __launch_bounds__(256) void k_gemm_mfma(const void* __restrict__ Av,
                                                   const unsigned short* __restrict__ WT,
                                                   const float* __restrict__ bias,
                                                   void* __restrict__ Cv,
                                                   int M, int N, int K) {
    constexpr int LDK = 40;
    __shared__ unsigned short As[64 * LDK];
    __shared__ unsigned short Bs[128 * LDK];
    const int tid = threadIdx.x;
    const int m0 = blockIdx.y * 64, n0 = blockIdx.x * 128;
    const int wave = tid >> 6, lane = tid & 63;
    const int wm = (wave >> 1) * 32;
    const int wn = (wave & 1) * 64;
    const int quad = lane >> 4, mrow = lane & 15;

    const int ar = tid >> 2;
    const int ak = (tid & 3) * 8;
    const bool arow_ok = (m0 + ar) < M;
    const size_t aoff = (size_t)(m0 + ar) * K + ak;
    const unsigned short* Bg0 = WT + (size_t)(n0 + ar) * K + ak;
    const unsigned short* Bg1 = WT + (size_t)(n0 + ar + 64) * K + ak;

    f32x4 acc[2][4] = {};

    for (int k0 = 0; k0 < K; k0 += 32) {
        u16x8 av = {};
        if (arow_ok) {
            if constexpr (AFP) {
                const float* Af = (const float*)Av + aoff + k0;
                float4 f0 = *(const float4*)Af;
                float4 f1 = *(const float4*)(Af + 4);
                av[0] = (short)f2b(f0.x); av[1] = (short)f2b(f0.y);
                av[2] = (short)f2b(f0.z); av[3] = (short)f2b(f0.w);
                av[4] = (short)f2b(f1.x); av[5] = (short)f2b(f1.y);
                av[6] = (short)f2b(f1.z); av[7] = (short)f2b(f1.w);
            } else {
                av = *(const u16x8*)((const unsigned short*)Av + aoff + k0);
            }
        }
        u16x8 bv0 = *(const u16x8*)(Bg0 + k0);
        u16x8 bv1 = *(const u16x8*)(Bg1 + k0);
        *(u16x8*)&As[ar * LDK + ak] = av;
        *(u16x8*)&Bs[ar * LDK + ak] = bv0;
        *(u16x8*)&Bs[(ar + 64) * LDK + ak] = bv1;
        __syncthreads();
        bf16x8 af[2], bf[4];
        #pragma unroll
        for (int mt = 0; mt < 2; ++mt)
            af[mt] = *(const bf16x8*)&As[(wm + mt * 16 + mrow) * LDK + quad * 8];
        #pragma unroll
        for (int nt = 0; nt < 4; ++nt)
            bf[nt] = *(const bf16x8*)&Bs[(wn + nt * 16 + mrow) * LDK + quad * 8];
        #pragma unroll
        for (int mt = 0; mt < 2; ++mt)
            #pragma unroll
            for (int nt = 0; nt < 4; ++nt)
                acc[mt][nt] = __builtin_amdgcn_mfma_f32_16x16x32_bf16(af[mt], bf[nt], acc[mt][nt], 0, 0, 0);
        __syncthreads();
    }

    float bn[4];
    #pragma unroll
    for (int nt = 0; nt < 4; ++nt) bn[nt] = bias[n0 + wn + nt * 16 + mrow];

    if constexpr (CMODE == 0) {
        unsigned short* C = (unsigned short*)Cv;
        #pragma unroll
        for (int mt = 0; mt < 2; ++mt) {
            #pragma unroll
            for (int r = 0; r < 4; ++r) {
                int row = m0 + wm + mt * 16 + quad * 4 + r;
                if (row < M) {
                    #pragma unroll
                    for (int nt = 0; nt < 4; ++nt) {
                        float v = fmaxf(acc[mt][nt][r] + bn[nt], 0.f);
                        C[(size_t)row * N + n0 + wn + nt * 16 + mrow] = f2b(v);
                    }
                }
            }
        }
    } else {
        float* C = (float*)Cv;
        #pragma unroll
        for (int mt = 0; mt < 2; ++mt) {
            #pragma unroll
            for (int r = 0; r < 4; ++r) {
                int row = m0 + wm + mt * 16 + quad * 4 + r;
                if (row < M) {
                    #pragma unroll
                    for (int nt = 0; nt < 4; ++nt)
                        C[(size_t)row * N + n0 + wn + nt * 16 + mrow] = acc[mt][nt][r] + bn[nt];
                }
            }
        }
    }
}

extern "C" void kernel_launch(void* const* d_in, const int* in_sizes, int n_in,
                              void* d_out, int out_size, void* d_ws, size_t ws_size,
                              hipStream_t stream) {
    const float* x   = (const float*)d_in[0];
    const float* ew  = (const float*)d_in[1];
    const float* W1  = (const float*)d_in[2];
    const float* b1  = (const float*)d_in[3];
    const float* W2  = (const float*)d_in[4];
    const float* b2  = (const float*)d_in[5];
    const float* W3  = (const float*)d_in[6];
    const float* b3  = (const float*)d_in[7];
    const float* Wf1 = (const float*)d_in[8];
    const float* bf1 = (const float*)d_in[9];
    const float* Wf2 = (const float*)d_in[10];
    const float* bf2 = (const float*)d_in[11];
    const int* ei    = (const int*)d_in[12];
    const int* batch = (const int*)d_in[13];
    float* out = (float*)d_out;
    (void)in_sizes; (void)n_in; (void)out_size; (void)ws_size;

    char* p = (char*)d_ws;
    auto alloc = [&](size_t bytes) -> char* {
        char* r = p;
        p += (bytes + 255) & ~(size_t)255;
        return r;
    };
    u64*   deg_cnt = (u64*)alloc((size_t)NNODES * 8);
    float* dinv   = (float*)alloc((size_t)NNODES * 4);
    unsigned* edges = (unsigned*)alloc((size_t)NNODES * DCAP * 4);  // padded CSR, 12.8 MB
    int*   gp     = (int*)  alloc((size_t)NGRAPH * 512 * 4);
    unsigned short* f1   = (unsigned short*)alloc((size_t)NGRAPH * 1024 * 2);
    unsigned short* wt1  = (unsigned short*)alloc((size_t)128 * 128 * 2);
    unsigned short* wt2  = (unsigned short*)alloc((size_t)256 * 128 * 2);
    unsigned short* wt3  = (unsigned short*)alloc((size_t)512 * 256 * 2);
    unsigned short* wtf1 = (unsigned short*)alloc((size_t)1024 * 512 * 2);
    unsigned short* wtf2 = (unsigned short*)alloc((size_t)128 * 1024 * 2);
    unsigned short* bufA = (unsigned short*)alloc((size_t)NPAD * 256 * 2);
    unsigned short* bufB = (unsigned short*)alloc((size_t)NPAD * 256 * 2);
    unsigned short* x16  = bufB;   // consumed by agg-1 before gemm-1 overwrites bufB
    // total ~68 MB

    const int MB128 = (NNODES + 127) / 128; // 391
    const int AGG = (NNODES + 3) / 4;       // 12500

    // graph preprocessing: 3 kernels
    k_init<<<1024, 256, 0, stream>>>(W1, W2, W3, Wf1, Wf2,
                                     wt1, wt2, wt3, wtf1, wtf2, deg_cnt, gp);
    k_count<<<(NEDGES / 4 + 255) / 256, 256, 0, stream>>>(
        (const int4*)ei, (const int4*)(ei + NEDGES), (const float4*)ew, deg_cnt, edges);
    k_cvt_prep<<<(NNODES * 32 + 255) / 256, 256, 0, stream>>>(x, deg_cnt, dinv, x16, NNODES * 32);

    // layer 1: Z1 = dinv*(x' + A@x'); h1' = dinv*relu(Z1@W1+b1)
    k_aggregate<128><<<AGG, 256, 0, stream>>>(x16, deg_cnt, edges, dinv, bufA);
    k_gemm128<0><<<dim3(1, MB128), 256, 0, stream>>>(bufA, wt1, b1, bufB, nullptr, nullptr, dinv, NNODES, 128, 128);
    // layer 2
    k_aggregate<128><<<AGG, 256, 0, stream>>>(bufB, deg_cnt, edges, dinv, bufA);
    k_gemm128<0><<<dim3(2, MB128), 256, 0, stream>>>(bufA, wt2, b2, bufB, nullptr, nullptr, dinv, NNODES, 256, 128);
    // layer 3 + fused pool (unscaled relu feeds the pool)
    k_aggregate<256><<<AGG, 256, 0, stream>>>(bufB, deg_cnt, edges, dinv, bufA);
    k_gemm128<2><<<dim3(4, MB128), 256, 0, stream>>>(bufA, wt3, b3, nullptr, batch, gp, nullptr, NNODES, 512, 256);

    // MLP head (legacy kernel, M=512)
    k_gemm_mfma<0, 1><<<dim3(8, NGRAPH / 64), 256, 0, stream>>>(gp, wtf1, bf1, f1, NGRAPH, 1024, 512);
    k_gemm_mfma<1, 0><<<dim3(1, NGRAPH / 64), 256, 0, stream>>>(f1, wtf2, bf2, out, NGRAPH, 128, 1024);
}

// Round 8
// 363.641 us; speedup vs baseline: 1.0131x; 1.0049x over previous
//
#include <hip/hip_runtime.h>

#define NNODES 50000
#define NPAD   50048   // 391 * 128; padded row count so 128-tile GEMM staging never faults
#define NEDGES 800000
#define NGRAPH 512
#define DCAP 64   // padded edge slots per node; Poisson(16) max ~37, P(>=64) ~ 1e-23

typedef short bf16x8 __attribute__((ext_vector_type(8)));
typedef unsigned short u16x8 __attribute__((ext_vector_type(8)));
typedef float f32x4 __attribute__((ext_vector_type(4)));
typedef unsigned long long u64;

// async global->LDS, 16B per lane (dest = wave-uniform base + lane*16, linear layout)
#define GLOAD16(g, l)                                                                 \
    __builtin_amdgcn_global_load_lds((const __attribute__((address_space(1))) unsigned*)(g), \
                                     (__attribute__((address_space(3))) unsigned*)(l), 16, 0, 0)

// ---------- bf16 <-> fp32 helpers ----------
static __device__ __forceinline__ float b2f(unsigned short u) {
    return __uint_as_float(((unsigned)u) << 16);
}
static __device__ __forceinline__ unsigned short f2b(float f) {
    unsigned u = __float_as_uint(f);
    unsigned r = (u + 0x7fffu + ((u >> 16) & 1u)) >> 16;  // round-nearest-even
    return (unsigned short)r;
}

// accumulate 8 bf16 (packed in uint4) * c into acc[8]
static __device__ __forceinline__ void accum8(float (&acc)[8], float c, uint4 v) {
    unsigned w[4] = {v.x, v.y, v.z, v.w};
    #pragma unroll
    for (int i = 0; i < 4; ++i) {
        acc[2 * i]     += c * __uint_as_float(w[i] << 16);
        acc[2 * i + 1] += c * __uint_as_float(w[i] & 0xffff0000u);
    }
}

// ---------- init: deg_cnt + gp setup, and all 5 weight transposes via LDS tiles ----------
// W[K][N] fp32 -> WT[N][K] bf16, 64x64 tiles, both global sides coalesced.
// 204 tiles total: W1 4, W2 8, W3 32, Wf1 128, Wf2 32. Blocks >=204 do setup only.
__global__ __launch_bounds__(256) void k_init(const float* __restrict__ W1, const float* __restrict__ W2,
                                              const float* __restrict__ W3, const float* __restrict__ Wf1,
                                              const float* __restrict__ Wf2,
                                              unsigned short* __restrict__ T1, unsigned short* __restrict__ T2,
                                              unsigned short* __restrict__ T3, unsigned short* __restrict__ Tf1,
                                              unsigned short* __restrict__ Tf2,
                                              u64* deg_cnt, int* gp) {
    int i = blockIdx.x * 256 + threadIdx.x;
    if (i < NNODES) deg_cnt[i] = (u64)(1u << 24);   // self-loop w=1 (8.24 fixed)
    if (i < NGRAPH * 512) gp[i] = 0;                // +0.0f bits; relu pool >= 0

    const int b = blockIdx.x;
    if (b >= 204) return;
    const float* W; unsigned short* T; int K, N, t0;
    if (b < 4)        { W = W1;  T = T1;  K = 128;  N = 128;  t0 = 0;   }
    else if (b < 12)  { W = W2;  T = T2;  K = 128;  N = 256;  t0 = 4;   }
    else if (b < 44)  { W = W3;  T = T3;  K = 256;  N = 512;  t0 = 12;  }
    else if (b < 172) { W = Wf1; T = Tf1; K = 512;  N = 1024; t0 = 44;  }
    else              { W = Wf2; T = Tf2; K = 1024; N = 128;  t0 = 172; }
    const int tile = b - t0;
    const int ntn = N >> 6;
    const int k0 = (tile / ntn) * 64, n0 = (tile % ntn) * 64;
    __shared__ float sm[64][65];
    const int t = threadIdx.x;
    const int rr = t >> 6, cc = t & 63;
    #pragma unroll
    for (int r = 0; r < 16; ++r) {
        int kl = r * 4 + rr;
        sm[kl][cc] = W[(size_t)(k0 + kl) * N + n0 + cc];
    }
    __syncthreads();
    #pragma unroll
    for (int r = 0; r < 16; ++r) {
        int nl = r * 4 + rr;
        T[(size_t)(n0 + nl) * K + k0 + cc] = f2b(sm[cc][nl]);
    }
}

// count + DIRECT padded-CSR placement (no scan, no fill pass):
// u64 atomic returns old count = this edge's slot; edges[d*DCAP + slot] = (bf16 ew, src16).
__global__ __launch_bounds__(256) void k_count(const int4* __restrict__ ei_s,
                                               const int4* __restrict__ ei_d,
                                               const float4* __restrict__ ew4,
                                               u64* deg_cnt,
                                               unsigned* __restrict__ edges) {
    int t = blockIdx.x * 256 + threadIdx.x;
    if (t >= NEDGES / 4) return;
    int4 ss = ei_s[t];
    int4 dd = ei_d[t];
    float4 ww = ew4[t];
    int s[4] = {ss.x, ss.y, ss.z, ss.w};
    int d[4] = {dd.x, dd.y, dd.z, dd.w};
    float w[4] = {ww.x, ww.y, ww.z, ww.w};
    int slot[4];
    #pragma unroll
    for (int u = 0; u < 4; ++u) {
        unsigned fixed = __float2uint_rn(w[u] * 16777216.0f);  // 2^24; ew in [0,1)
        u64 old = atomicAdd(&deg_cnt[d[u]], ((u64)1 << 32) | fixed);
        slot[u] = (int)(old >> 32);
        if (slot[u] > DCAP - 1) slot[u] = DCAP - 1;  // never fires (safety)
    }
    #pragma unroll
    for (int u = 0; u < 4; ++u)
        edges[((unsigned)d[u] << 6) | slot[u]] = ((unsigned)f2b(w[u]) << 16) | (unsigned)s[u];
}

// fp32 -> bf16 with per-row dinv scale (computed inline from deg_cnt; also writes dinv[])
__global__ void k_cvt_prep(const float* __restrict__ X, const u64* __restrict__ deg_cnt,
                           float* __restrict__ dinv, unsigned short* __restrict__ Y, int n4) {
    int i = blockIdx.x * 256 + threadIdx.x;
    if (i < n4) {
        int row = i >> 5;   // 32 float4 per 128-wide row
        float d = rsqrtf((float)(unsigned)(deg_cnt[row] & 0xffffffffull) * 5.9604645e-8f);
        if ((i & 31) == 0) dinv[row] = d;
        float4 v = ((const float4*)X)[i];
        uint2 o;
        o.x = (unsigned)f2b(v.x * d) | ((unsigned)f2b(v.y * d) << 16);
        o.y = (unsigned)f2b(v.z * d) | ((unsigned)f2b(v.w * d) << 16);
        ((uint2*)Y)[i] = o;
    }
}

// ---------- aggregation: Z[d,:] = dinv[d] * (X'[d,:] + sum_e ew_e * X'[src_e,:]) ----------
// wave-per-(node, feature-slice). SLICES=1: round-2 verified form. SLICES=2 (F=256):
// slice = bid&1 -> under round-robin block->XCD dispatch, slice parity == XCD parity,
// so each XCD's L2 works on a 12.8MB half-table instead of 25.6MB (round-3-verified
// fetch model, ~187->~115MB). Geometry per slice-block is identical to the F=128 form
// (16 lanes/row, 4 edges in flight): loop work splits across slice-waves, only the
// prologue + reduce duplicate. 16B dwordx4 gathers, rotating 2-deep pipeline,
// weight-0 masked tail, cross-group shfl reduce, 16B stores by group 0.
template <int F, int SLICES>
__global__ __launch_bounds__(256) void k_aggregate(const unsigned short* __restrict__ X,
                                                   const u64* __restrict__ deg_cnt,
                                                   const unsigned* __restrict__ edges,
                                                   const float* __restrict__ dinv,
                                                   unsigned short* __restrict__ Z) {
    constexpr int FS = F / SLICES;     // features handled per block
    constexpr int LPR = FS / 8;        // lanes per source row-slice (16 or 32)
    constexpr int GRP = 64 / LPR;      // edges per step (4 or 2)
    constexpr int STEP = GRP * 2;      // edges per pair-iteration (8 or 4)
    const int bid = blockIdx.x;
    const int slice = (SLICES == 1) ? 0 : (bid & (SLICES - 1));
    const int chunk = (SLICES == 1) ? bid : (bid / SLICES);
    const int wave = threadIdx.x >> 6, lane = threadIdx.x & 63;
    const int node = chunk * 4 + wave;
    if (node >= NNODES) return;
    const int sub = lane & (LPR - 1);
    const int grp = lane / LPR;
    const int fo = slice * FS + sub * 8;
    const unsigned short* Xf = X + fo;
    const float di = dinv[node];
    const int cnt = (int)(deg_cnt[node] >> 32);
    const unsigned* erow = edges + ((unsigned)node << 6);

    // self row-slice: issue early, consumed in epilogue
    const uint4 selfv = *(const uint4*)(Xf + (size_t)node * F);

    float acc[8] = {};

    const int e0 = grp;
    const int nb = (cnt + STEP - 1) / STEP;   // pair-iterations (wave-uniform)

    unsigned pa0 = 0, pb0 = 0, pa1 = 0, pb1 = 0;
    uint4 va0 = {}, vb0 = {};
    if (nb > 0) {
        int ea = e0, eb = e0 + GRP;
        pa0 = (ea < cnt) ? erow[ea] : 0u;
        pb0 = (eb < cnt) ? erow[eb] : 0u;
        va0 = *(const uint4*)(Xf + (size_t)(pa0 & 0xffffu) * F);
        vb0 = *(const uint4*)(Xf + (size_t)(pb0 & 0xffffu) * F);
        if (nb > 1) {
            int ea1 = e0 + STEP, eb1 = ea1 + GRP;
            pa1 = (ea1 < cnt) ? erow[ea1] : 0u;
            pb1 = (eb1 < cnt) ? erow[eb1] : 0u;
        }
    }
    for (int p = 0; p < nb; ++p) {
        uint4 va1 = {}, vb1 = {};
        unsigned pa2 = 0, pb2 = 0;
        if (p + 1 < nb) {
            va1 = *(const uint4*)(Xf + (size_t)(pa1 & 0xffffu) * F);
            vb1 = *(const uint4*)(Xf + (size_t)(pb1 & 0xffffu) * F);
            if (p + 2 < nb) {
                int ea = e0 + (p + 2) * STEP, eb = ea + GRP;
                pa2 = (ea < cnt) ? erow[ea] : 0u;
                pb2 = (eb < cnt) ? erow[eb] : 0u;
            }
        }
        accum8(acc, b2f((unsigned short)(pa0 >> 16)), va0);
        accum8(acc, b2f((unsigned short)(pb0 >> 16)), vb0);
        pa0 = pa1; pb0 = pb1; va0 = va1; vb0 = vb1;
        pa1 = pa2; pb1 = pb2;
    }

    // cross-group reduce
    #pragma unroll
    for (int j = 0; j < 8; ++j) {
        if constexpr (GRP == 4) acc[j] += __shfl_xor(acc[j], 16, 64);
        acc[j] += __shfl_xor(acc[j], 32, 64);
    }

    if (grp == 0) {
        unsigned w[4] = {selfv.x, selfv.y, selfv.z, selfv.w};
        unsigned o[4];
        #pragma unroll
        for (int i = 0; i < 4; ++i) {
            float s0 = __uint_as_float(w[i] << 16);
            float s1 = __uint_as_float(w[i] & 0xffff0000u);
            unsigned short c0 = f2b(di * (acc[2 * i] + s0));
            unsigned short c1 = f2b(di * (acc[2 * i + 1] + s1));
            o[i] = (unsigned)c0 | ((unsigned)c1 << 16);
        }
        uint4 ov; ov.x = o[0]; ov.y = o[1]; ov.z = o[2]; ov.w = o[3];
        *(uint4*)(Z + (size_t)node * F + fo) = ov;
    }
}

// ---------- m97-structure GEMM, 2-phase double-buffered (T3-minimum) ----------
// 128x128 tile, 4 waves (2x2), each 64x64 = 4x4 16x16x32 fragments. BK=32.
// Double-buffered linear LDS [2][128][32]; next tile's global_load_lds issued BEFORE
// current tile's ds_read+MFMA -> loads fly under compute; one vmcnt-drain barrier/tile.
// A rows readable up to next multiple of 128 (NPAD); OOB-row garbage only pollutes
// accumulators discarded by row<M guards.
// Bijective XCD chunking (m204): each XCD owns a contiguous m-range for all n-blocks.
// CMODE 0: bf16 store + relu + optional rscale. 2: fused per-graph relu+max-pool.
template <int CMODE>
__global__ __launch_bounds__(256) void k_gemm128(const unsigned short* __restrict__ A,
                                                 const unsigned short* __restrict__ WT,
                                                 const float* __restrict__ bias,
                                                 unsigned short* __restrict__ C,
                                                 const int* __restrict__ batch,
                                                 int* __restrict__ gp,
                                                 const float* __restrict__ rscale,
                                                 int M, int N, int K) {
    __shared__ unsigned short As[2][128 * 32];
    __shared__ unsigned short Bs[2][128 * 32];
    const int tid = threadIdx.x;

    // bijective XCD remap of flat block id (xcd = f % 8 under round-robin dispatch)
    const int nwg = gridDim.x * gridDim.y;
    const int f = blockIdx.y * gridDim.x + blockIdx.x;
    const int q = nwg >> 3, r = nwg & 7;
    const int xcd = f & 7, idx = f >> 3;
    const int w = (xcd < r) ? xcd * (q + 1) + idx : r * (q + 1) + (xcd - r) * q + idx;
    const int m0 = (w / gridDim.x) * 128;
    const int n0 = (w % gridDim.x) * 128;

    const int wave = tid >> 6, lane = tid & 63;
    const int wm = (wave >> 1) * 64, wn = (wave & 1) * 64;
    const int quad = lane >> 4, mrow = lane & 15;

    const int sr = tid >> 2;              // staging row 0..63
    const int sc = (tid & 3) * 8;         // staging col (shorts)
    const unsigned short* Ag0 = A + (size_t)(m0 + sr) * K + sc;
    const unsigned short* Ag1 = A + (size_t)(m0 + 64 + sr) * K + sc;
    const unsigned short* Bg0 = WT + (size_t)(n0 + sr) * K + sc;
    const unsigned short* Bg1 = WT + (size_t)(n0 + 64 + sr) * K + sc;
    const int so0 = sr * 32 + sc, so1 = (64 + sr) * 32 + sc;

    f32x4 acc[4][4] = {};
    const int nsteps = K >> 5;

    // prologue: stage tile 0 into buffer 0
    GLOAD16(Ag0, &As[0][so0]);
    GLOAD16(Ag1, &As[0][so1]);
    GLOAD16(Bg0, &Bs[0][so0]);
    GLOAD16(Bg1, &Bs[0][so1]);
    __syncthreads();   // vmcnt(0) drain + barrier

    for (int step = 0; step < nsteps; ++step) {
        const int cur = step & 1;
        if (step + 1 < nsteps) {           // issue next tile while computing current
            const int k1 = (step + 1) << 5;
            GLOAD16(Ag0 + k1, &As[cur ^ 1][so0]);
            GLOAD16(Ag1 + k1, &As[cur ^ 1][so1]);
            GLOAD16(Bg0 + k1, &Bs[cur ^ 1][so0]);
            GLOAD16(Bg1 + k1, &Bs[cur ^ 1][so1]);
        }
        bf16x8 af[4], bf[4];
        #pragma unroll
        for (int mt = 0; mt < 4; ++mt)
            af[mt] = *(const bf16x8*)&As[cur][(wm + mt * 16 + mrow) * 32 + quad * 8];
        #pragma unroll
        for (int nt = 0; nt < 4; ++nt)
            bf[nt] = *(const bf16x8*)&Bs[cur][(wn + nt * 16 + mrow) * 32 + quad * 8];
        #pragma unroll
        for (int mt = 0; mt < 4; ++mt)
            #pragma unroll
            for (int nt = 0; nt < 4; ++nt)
                acc[mt][nt] = __builtin_amdgcn_mfma_f32_16x16x32_bf16(af[mt], bf[nt], acc[mt][nt], 0, 0, 0);
        __syncthreads();   // drains prefetch vmcnt + this tile's lgkm; gates buffer reuse
    }

    float bn[4];
    #pragma unroll
    for (int nt = 0; nt < 4; ++nt) bn[nt] = bias[n0 + wn + nt * 16 + mrow];

    if constexpr (CMODE == 0) {
        #pragma unroll
        for (int mt = 0; mt < 4; ++mt) {
            #pragma unroll
            for (int r4 = 0; r4 < 4; ++r4) {
                int row = m0 + wm + mt * 16 + quad * 4 + r4;
                if (row < M) {
                    float rs = rscale ? rscale[row] : 1.0f;
                    #pragma unroll
                    for (int nt = 0; nt < 4; ++nt) {
                        float v = fmaxf(acc[mt][nt][r4] + bn[nt], 0.f) * rs;
                        C[(size_t)row * N + n0 + wn + nt * 16 + mrow] = f2b(v);
                    }
                }
            }
        }
    } else {
        // per-wave pool: wave covers 64 rows -> spans <=2 graphs (min graph size 97)
        const int wr0 = m0 + wm;
        int g0i = wr0 < M ? wr0 : M - 1;
        const int g0 = batch[g0i];
        int lastr = wr0 + 63; if (lastr >= M) lastr = M - 1;
        const int gl = batch[lastr];
        bool rok[16]; int gid[16];
        #pragma unroll
        for (int mt = 0; mt < 4; ++mt)
            #pragma unroll
            for (int r4 = 0; r4 < 4; ++r4) {
                int row = wr0 + mt * 16 + quad * 4 + r4;
                rok[mt * 4 + r4] = row < M;
                gid[mt * 4 + r4] = (row < M) ? batch[row] : -1;
            }
        #pragma unroll
        for (int nt = 0; nt < 4; ++nt) {
            float v0 = 0.f, v1 = 0.f;
            #pragma unroll
            for (int mt = 0; mt < 4; ++mt)
                #pragma unroll
                for (int r4 = 0; r4 < 4; ++r4)
                    if (rok[mt * 4 + r4]) {
                        float v = fmaxf(acc[mt][nt][r4] + bn[nt], 0.f);
                        if (gid[mt * 4 + r4] == g0) v0 = fmaxf(v0, v);
                        else v1 = fmaxf(v1, v);
                    }
            v0 = fmaxf(v0, __shfl_xor(v0, 16, 64));
            v0 = fmaxf(v0, __shfl_xor(v0, 32, 64));
            v1 = fmaxf(v1, __shfl_xor(v1, 16, 64));
            v1 = fmaxf(v1, __shfl_xor(v1, 32, 64));
            if (quad == 0) {
                int c = n0 + wn + nt * 16 + mrow;
                atomicMax(&gp[(size_t)g0 * N + c], __float_as_int(v0));
                if (gl != g0) atomicMax(&gp[(size_t)gl * N + c], __float_as_int(v1));
            }
        }
    }
}

// ---------- legacy GEMM for the small MLP head (M=512) ----------
// block 64(M) x 128(N), 4 waves (2x2 of 32x64), BK=32, 16x16x32 MFMA.
// CMODE 0: bf16 store + relu. 1: fp32 store, no relu. AFP: A is fp32.
template <int CMODE, int AFP>
__global__ __launch_bounds__(256) void k_gemm_mfma(const void* __restrict__ Av,
                                                   const unsigned short* __restrict__ WT,
                                                   const float* __restrict__ bias,
                                                   void* __restrict__ Cv,
                                                   int M, int N, int K) {
    constexpr int LDK = 40;
    __shared__ unsigned short As[64 * LDK];
    __shared__ unsigned short Bs[128 * LDK];
    const int tid = threadIdx.x;
    const int m0 = blockIdx.y * 64, n0 = blockIdx.x * 128;
    const int wave = tid >> 6, lane = tid & 63;
    const int wm = (wave >> 1) * 32;
    const int wn = (wave & 1) * 64;
    const int quad = lane >> 4, mrow = lane & 15;

    const int ar = tid >> 2;
    const int ak = (tid & 3) * 8;
    const bool arow_ok = (m0 + ar) < M;
    const size_t aoff = (size_t)(m0 + ar) * K + ak;
    const unsigned short* Bg0 = WT + (size_t)(n0 + ar) * K + ak;
    const unsigned short* Bg1 = WT + (size_t)(n0 + ar + 64) * K + ak;

    f32x4 acc[2][4] = {};

    for (int k0 = 0; k0 < K; k0 += 32) {
        u16x8 av = {};
        if (arow_ok) {
            if constexpr (AFP) {
                const float* Af = (const float*)Av + aoff + k0;
                float4 f0 = *(const float4*)Af;
                float4 f1 = *(const float4*)(Af + 4);
                av[0] = (short)f2b(f0.x); av[1] = (short)f2b(f0.y);
                av[2] = (short)f2b(f0.z); av[3] = (short)f2b(f0.w);
                av[4] = (short)f2b(f1.x); av[5] = (short)f2b(f1.y);
                av[6] = (short)f2b(f1.z); av[7] = (short)f2b(f1.w);
            } else {
                av = *(const u16x8*)((const unsigned short*)Av + aoff + k0);
            }
        }
        u16x8 bv0 = *(const u16x8*)(Bg0 + k0);
        u16x8 bv1 = *(const u16x8*)(Bg1 + k0);
        *(u16x8*)&As[ar * LDK + ak] = av;
        *(u16x8*)&Bs[ar * LDK + ak] = bv0;
        *(u16x8*)&Bs[(ar + 64) * LDK + ak] = bv1;
        __syncthreads();
        bf16x8 af[2], bf[4];
        #pragma unroll
        for (int mt = 0; mt < 2; ++mt)
            af[mt] = *(const bf16x8*)&As[(wm + mt * 16 + mrow) * LDK + quad * 8];
        #pragma unroll
        for (int nt = 0; nt < 4; ++nt)
            bf[nt] = *(const bf16x8*)&Bs[(wn + nt * 16 + mrow) * LDK + quad * 8];
        #pragma unroll
        for (int mt = 0; mt < 2; ++mt)
            #pragma unroll
            for (int nt = 0; nt < 4; ++nt)
                acc[mt][nt] = __builtin_amdgcn_mfma_f32_16x16x32_bf16(af[mt], bf[nt], acc[mt][nt], 0, 0, 0);
        __syncthreads();
    }

    float bn[4];
    #pragma unroll
    for (int nt = 0; nt < 4; ++nt) bn[nt] = bias[n0 + wn + nt * 16 + mrow];

    if constexpr (CMODE == 0) {
        unsigned short* C = (unsigned short*)Cv;
        #pragma unroll
        for (int mt = 0; mt < 2; ++mt) {
            #pragma unroll
            for (int r = 0; r < 4; ++r) {
                int row = m0 + wm + mt * 16 + quad * 4 + r;
                if (row < M) {
                    #pragma unroll
                    for (int nt = 0; nt < 4; ++nt) {
                        float v = fmaxf(acc[mt][nt][r] + bn[nt], 0.f);
                        C[(size_t)row * N + n0 + wn + nt * 16 + mrow] = f2b(v);
                    }
                }
            }
        }
    } else {
        float* C = (float*)Cv;
        #pragma unroll
        for (int mt = 0; mt < 2; ++mt) {
            #pragma unroll
            for (int r = 0; r < 4; ++r) {
                int row = m0 + wm + mt * 16 + quad * 4 + r;
                if (row < M) {
                    #pragma unroll
                    for (int nt = 0; nt < 4; ++nt)
                        C[(size_t)row * N + n0 + wn + nt * 16 + mrow] = acc[mt][nt][r] + bn[nt];
                }
            }
        }
    }
}

extern "C" void kernel_launch(void* const* d_in, const int* in_sizes, int n_in,
                              void* d_out, int out_size, void* d_ws, size_t ws_size,
                              hipStream_t stream) {
    const float* x   = (const float*)d_in[0];
    const float* ew  = (const float*)d_in[1];
    const float* W1  = (const float*)d_in[2];
    const float* b1  = (const float*)d_in[3];
    const float* W2  = (const float*)d_in[4];
    const float* b2  = (const float*)d_in[5];
    const float* W3  = (const float*)d_in[6];
    const float* b3  = (const float*)d_in[7];
    const float* Wf1 = (const float*)d_in[8];
    const float* bf1 = (const float*)d_in[9];
    const float* Wf2 = (const float*)d_in[10];
    const float* bf2 = (const float*)d_in[11];
    const int* ei    = (const int*)d_in[12];
    const int* batch = (const int*)d_in[13];
    float* out = (float*)d_out;
    (void)in_sizes; (void)n_in; (void)out_size; (void)ws_size;

    char* p = (char*)d_ws;
    auto alloc = [&](size_t bytes) -> char* {
        char* r = p;
        p += (bytes + 255) & ~(size_t)255;
        return r;
    };
    u64*   deg_cnt = (u64*)alloc((size_t)NNODES * 8);
    float* dinv   = (float*)alloc((size_t)NNODES * 4);
    unsigned* edges = (unsigned*)alloc((size_t)NNODES * DCAP * 4);  // padded CSR, 12.8 MB
    int*   gp     = (int*)  alloc((size_t)NGRAPH * 512 * 4);
    unsigned short* f1   = (unsigned short*)alloc((size_t)NGRAPH * 1024 * 2);
    unsigned short* wt1  = (unsigned short*)alloc((size_t)128 * 128 * 2);
    unsigned short* wt2  = (unsigned short*)alloc((size_t)256 * 128 * 2);
    unsigned short* wt3  = (unsigned short*)alloc((size_t)512 * 256 * 2);
    unsigned short* wtf1 = (unsigned short*)alloc((size_t)1024 * 512 * 2);
    unsigned short* wtf2 = (unsigned short*)alloc((size_t)128 * 1024 * 2);
    unsigned short* bufA = (unsigned short*)alloc((size_t)NPAD * 256 * 2);
    unsigned short* bufB = (unsigned short*)alloc((size_t)NPAD * 256 * 2);
    unsigned short* x16  = bufB;   // consumed by agg-1 before gemm-1 overwrites bufB
    // total ~68 MB

    const int MB128 = (NNODES + 127) / 128; // 391
    const int AGG = (NNODES + 3) / 4;       // 12500

    // graph preprocessing: 3 kernels
    k_init<<<1024, 256, 0, stream>>>(W1, W2, W3, Wf1, Wf2,
                                     wt1, wt2, wt3, wtf1, wtf2, deg_cnt, gp);
    k_count<<<(NEDGES / 4 + 255) / 256, 256, 0, stream>>>(
        (const int4*)ei, (const int4*)(ei + NEDGES), (const float4*)ew, deg_cnt, edges);
    k_cvt_prep<<<(NNODES * 32 + 255) / 256, 256, 0, stream>>>(x, deg_cnt, dinv, x16, NNODES * 32);

    // layer 1: Z1 = dinv*(x' + A@x'); h1' = dinv*relu(Z1@W1+b1)
    k_aggregate<128, 1><<<AGG, 256, 0, stream>>>(x16, deg_cnt, edges, dinv, bufA);
    k_gemm128<0><<<dim3(1, MB128), 256, 0, stream>>>(bufA, wt1, b1, bufB, nullptr, nullptr, dinv, NNODES, 128, 128);
    // layer 2
    k_aggregate<128, 1><<<AGG, 256, 0, stream>>>(bufB, deg_cnt, edges, dinv, bufA);
    k_gemm128<0><<<dim3(2, MB128), 256, 0, stream>>>(bufA, wt2, b2, bufB, nullptr, nullptr, dinv, NNODES, 256, 128);
    // layer 3 + fused pool (unscaled relu feeds the pool); feature-sliced aggregate (S=2)
    k_aggregate<256, 2><<<AGG * 2, 256, 0, stream>>>(bufB, deg_cnt, edges, dinv, bufA);
    k_gemm128<2><<<dim3(4, MB128), 256, 0, stream>>>(bufA, wt3, b3, nullptr, batch, gp, nullptr, NNODES, 512, 256);

    // MLP head (legacy kernel, M=512)
    k_gemm_mfma<0, 1><<<dim3(8, NGRAPH / 64), 256, 0, stream>>>(gp, wtf1, bf1, f1, NGRAPH, 1024, 512);
    k_gemm_mfma<1, 0><<<dim3(1, NGRAPH / 64), 256, 0, stream>>>(f1, wtf2, bf2, out, NGRAPH, 128, 1024);
}